// Round 12
// baseline (184.225 us; speedup 1.0000x reference)
//
#include <hip/hip_runtime.h>

// Range-aware attention, bf16 MFMA pipeline.
// B=2, S=2048, D=1024, H=16, dk=64. EPS=0.1.

typedef __bf16 bf16x8 __attribute__((ext_vector_type(8)));
typedef float f32x4 __attribute__((ext_vector_type(4)));
typedef float f32x16 __attribute__((ext_vector_type(16)));

#define EPSG 0.1f
// q pre-scale: 1/sqrt(dk) * log2(e)  -> scores come out in log2 domain
#define QSCALE 0.180336880f

__device__ __forceinline__ unsigned short f2bf(float f) {
  unsigned int u = __float_as_uint(f);
  u += 0x7FFFu + ((u >> 16) & 1u);   // RNE
  return (unsigned short)(u >> 16);
}

__device__ __forceinline__ unsigned cvt_pk_bf16(float a, float b) {
  unsigned r;
  asm("v_cvt_pk_bf16_f32 %0, %1, %2" : "=v"(r) : "v"(a), "v"(b));
  return r;  // lo16 = bf16(a), hi16 = bf16(b)
}

__device__ __forceinline__ void gload_lds16(const void* g, void* l) {
  __builtin_amdgcn_global_load_lds(
      (const __attribute__((address_space(1))) void*)g,
      (__attribute__((address_space(3))) void*)l, 16, 0, 0);
}

__device__ __forceinline__ f32x16 mfma32(bf16x8 a, bf16x8 b, f32x16 c) {
  return __builtin_amdgcn_mfma_f32_32x32x16_bf16(a, b, c, 0, 0, 0);
}

// ---------------- fp32 -> bf16 cast ----------------
__global__ __launch_bounds__(256) void cvt_f32_bf16(const float* __restrict__ in,
                                                    unsigned short* __restrict__ out,
                                                    int n4) {
  int i = blockIdx.x * 256 + threadIdx.x;
  if (i < n4) {
    float4 v = ((const float4*)in)[i];
    ushort4 o;
    o.x = f2bf(v.x); o.y = f2bf(v.y); o.z = f2bf(v.z); o.w = f2bf(v.w);
    ((ushort4*)out)[i] = o;
  }
}

// ---------------- shared GEMM pieces ----------------
__device__ __forceinline__ void stage128x64(const unsigned short* __restrict__ g,
                                            long ldb, long row0, long k0b,
                                            unsigned short* lds, int w, int l) {
  const char* gp = (const char*)g + (row0 + (long)(w * 8 + (l >> 3))) * ldb + k0b +
                   (long)(((l & 7) ^ (l >> 3)) << 4);
  char* lp = (char*)lds + w * 1024;
#pragma unroll
  for (int i = 0; i < 4; ++i) {
    gload_lds16(gp + (long)i * 32 * ldb, lp + i * 4096);
  }
}

__device__ __forceinline__ bf16x8 frag_ld(const unsigned short* lds, int row, int cb) {
  return *(const bf16x8*)((const char*)lds + row * 128 + (cb ^ ((row & 7) << 4)));
}

// XCD-chunked bijective block swizzle (T1): nwg must be divisible by 8.
__device__ __forceinline__ int xcd_swz(int lin, int nwg) {
  return (lin & 7) * (nwg >> 3) + (lin >> 3);
}

// 128x128 output tile, K=1024, A and B^T both row-major with 2048-byte rows.
__device__ __forceinline__ void gemm_loop(const unsigned short* __restrict__ A,
                                          const unsigned short* __restrict__ Bm,
                                          long m0, long n0,
                                          unsigned short* aT, unsigned short* bT,
                                          int w, int l, f32x4 acc[4][4]) {
  const int wr = (w >> 1) * 64, wc = (w & 1) * 64;
  const int l15 = l & 15;
  for (int ks = 0; ks < 1024; ks += 64) {
    __syncthreads();
    stage128x64(A, 2048, m0, (long)ks * 2, aT, w, l);
    stage128x64(Bm, 2048, n0, (long)ks * 2, bT, w, l);
    __syncthreads();
#pragma unroll
    for (int kk = 0; kk < 2; ++kk) {
      const int cb = kk * 64 + (l >> 4) * 16;
      bf16x8 af[4], bfr[4];
#pragma unroll
      for (int t = 0; t < 4; ++t) af[t] = frag_ld(aT, wr + t * 16 + l15, cb);
#pragma unroll
      for (int t = 0; t < 4; ++t) bfr[t] = frag_ld(bT, wc + t * 16 + l15, cb);
#pragma unroll
      for (int mt = 0; mt < 4; ++mt)
#pragma unroll
        for (int nt = 0; nt < 4; ++nt)
          acc[mt][nt] = __builtin_amdgcn_mfma_f32_16x16x32_bf16(af[mt], bfr[nt],
                                                                acc[mt][nt], 0, 0, 0);
    }
  }
}

// ---------------- QKV projection + clamp + layout scatter ----------------
// q stored PRE-SCALED by QSCALE (1/8 * log2e).  q,k -> [B*H][S][64]; v -> [B*H][64][S].
__global__ __launch_bounds__(256) void qkv_gemm(
    const unsigned short* __restrict__ xb, const unsigned short* __restrict__ wb,
    const float* __restrict__ bias,
    const float* __restrict__ akmin, const float* __restrict__ akmax,
    const float* __restrict__ avmin, const float* __restrict__ avmax,
    unsigned short* __restrict__ qo, unsigned short* __restrict__ ko,
    unsigned short* __restrict__ vto) {
  __shared__ __align__(16) unsigned short aT[128 * 64];
  __shared__ __align__(16) unsigned short bT[128 * 64];
  const int tid = threadIdx.x, l = tid & 63, w = tid >> 6;
  const int swz = xcd_swz(blockIdx.y * 24 + blockIdx.x, 24 * 32);
  const int bx = swz % 24, by = swz / 24;
  const long m0 = (long)by * 128, n0 = (long)bx * 128;
  f32x4 acc[4][4] = {};
  gemm_loop(xb, wb, m0, n0, aT, bT, w, l, acc);

  const int wr = (w >> 1) * 64, wc = (w & 1) * 64;
  const int l15 = l & 15, lg = l >> 4;
  const int t = (int)(n0 >> 10);  // uniform per block
#pragma unroll
  for (int nt = 0; nt < 4; ++nt) {
    const int n = (int)n0 + wc + nt * 16 + l15;
    const float bv = bias[n];
    const int h = (n >> 6) & 15, d = n & 63;
#pragma unroll
    for (int mt = 0; mt < 4; ++mt) {
      const long s0 = m0 + wr + mt * 16 + lg * 4;
      const int b = (int)(s0 >> 11), s_lo = (int)(s0 & 2047);
      const int bh = b * 16 + h;
      if (t == 0) {
#pragma unroll
        for (int j = 0; j < 4; ++j) {
          float v = (acc[mt][nt][j] + bv) * QSCALE;
          qo[((long)bh * 2048 + s_lo + j) * 64 + d] = f2bf(v);
        }
      } else if (t == 1) {
        const int ai = bh * 64 + d;
        const float amn = akmin[ai], amx = akmax[ai];
#pragma unroll
        for (int j = 0; j < 4; ++j) {
          float v = acc[mt][nt][j] + bv;
          float lo = fmaxf(v - EPSG, amn);
          float hi = fminf(v + EPSG, amx);
          lo = fminf(lo, hi);
          v = fmaxf(lo, fminf(v, hi));
          ko[((long)bh * 2048 + s_lo + j) * 64 + d] = f2bf(v);
        }
      } else {
        const int ai = bh * 64 + d;
        const float amn = avmin[ai], amx = avmax[ai];
        ushort4 pk;
        unsigned short* pp = (unsigned short*)&pk;
#pragma unroll
        for (int j = 0; j < 4; ++j) {
          float v = acc[mt][nt][j] + bv;
          float lo = fmaxf(v - EPSG, amn);
          float hi = fminf(v + EPSG, amx);
          lo = fminf(lo, hi);
          v = fmaxf(lo, fminf(v, hi));
          pp[j] = f2bf(v);
        }
        *(ushort4*)(vto + ((long)bh * 64 + d) * 2048 + s_lo) = pk;
      }
    }
  }
}

// ---------------- flash attention (32x32 MFMA, T4 counted-vmcnt pipeline) ----
// grid 1024 blocks XCD-chunked -> (qt 0..31, bh); 2 waves x 32 q-rows.
// K/V TRIPLE-buffered in LDS; stage(kt+2) issued each iter; loop waits
// vmcnt(8) (next tile landed, tile-after stays IN FLIGHT across a RAW
// s_barrier — __syncthreads would drain vmcnt(0), the measured invariant
// across 4 flat rounds). P never touches LDS (cvt_pk + shfl_xor(32)).
__global__ __launch_bounds__(128) void attn_fwd(
    const unsigned short* __restrict__ q, const unsigned short* __restrict__ k,
    const unsigned short* __restrict__ vt, unsigned short* __restrict__ o) {
  __shared__ __align__(16) unsigned short kT[3][64 * 64];
  __shared__ __align__(16) unsigned short vT[3][64 * 64];
  const int tid = threadIdx.x, l = tid & 63, w = tid >> 6;  // w in {0,1}
  const int l31 = l & 31, hi = l >> 5;

  const int linear = blockIdx.y * 32 + blockIdx.x;
  const int idx = linear >> 3;
  const int bh = (linear & 7) * 4 + (idx >> 5);
  const int qt = idx & 31;

  const char* kbC = (const char*)(k + (long)bh * 2048 * 64);
  const char* vbC = (const char*)(vt + (long)bh * 64 * 2048);

  // Q register fragments: B[k=d][col=q=l31], k = hi*8+i, one frag per 16-d chunk
  const unsigned short* qrow_p =
      q + ((long)bh * 2048 + qt * 64 + w * 32 + l31) * 64 + hi * 8;
  const bf16x8 qf0 = *(const bf16x8*)(qrow_p + 0);
  const bf16x8 qf1 = *(const bf16x8*)(qrow_p + 16);
  const bf16x8 qf2 = *(const bf16x8*)(qrow_p + 32);
  const bf16x8 qf3 = *(const bf16x8*)(qrow_p + 48);

  float m_run = -1e30f, l_part = 0.f;
  f32x16 oacc0 = {};  // d 0..31
  f32x16 oacc1 = {};  // d 32..63

  const int srow = l >> 3;
  const int schk = ((l & 7) ^ srow) << 4;
  const int gb = hi * 16;  // fragment k-offset within a row (bytes)

#define STAGE_KV(kt_, buf_)                                                  \
  do {                                                                       \
    const char* sK = kbC + (long)((kt_)*64 + w * 8 + srow) * 128 + schk;     \
    char* dK = (char*)kT[buf_] + w * 1024;                                   \
    gload_lds16(sK, dK);                                                     \
    gload_lds16(sK + 16 * 128, dK + 2048);                                   \
    gload_lds16(sK + 32 * 128, dK + 4096);                                   \
    gload_lds16(sK + 48 * 128, dK + 6144);                                   \
    const char* sV = vbC + (long)(w * 8 + srow) * 4096 + (long)(kt_)*128 + schk; \
    char* dV = (char*)vT[buf_] + w * 1024;                                   \
    gload_lds16(sV, dV);                                                     \
    gload_lds16(sV + 16 * 4096, dV + 2048);                                  \
    gload_lds16(sV + 32 * 4096, dV + 4096);                                  \
    gload_lds16(sV + 48 * 4096, dV + 6144);                                  \
  } while (0)

  auto COMPUTE = [&](const unsigned short* kTc, const unsigned short* vTc) {
    // S^T tiles: sc0 = kv 0..31, sc1 = kv 32..63 (lane: q=l31)
    f32x16 sc0 = {}, sc1 = {};
    __builtin_amdgcn_s_setprio(1);
    {
      bf16x8 kf;
      kf = frag_ld(kTc, l31, gb + 0);  sc0 = mfma32(kf, qf0, sc0);
      kf = frag_ld(kTc, l31, gb + 32); sc0 = mfma32(kf, qf1, sc0);
      kf = frag_ld(kTc, l31, gb + 64); sc0 = mfma32(kf, qf2, sc0);
      kf = frag_ld(kTc, l31, gb + 96); sc0 = mfma32(kf, qf3, sc0);
      kf = frag_ld(kTc, 32 + l31, gb + 0);  sc1 = mfma32(kf, qf0, sc1);
      kf = frag_ld(kTc, 32 + l31, gb + 32); sc1 = mfma32(kf, qf1, sc1);
      kf = frag_ld(kTc, 32 + l31, gb + 64); sc1 = mfma32(kf, qf2, sc1);
      kf = frag_ld(kTc, 32 + l31, gb + 96); sc1 = mfma32(kf, qf3, sc1);
    }
    __builtin_amdgcn_s_setprio(0);

    // tile max (tree) over this lane's 32 values
    float a0 = fmaxf(fmaxf(sc0[0], sc0[1]), fmaxf(sc0[2], sc0[3]));
    float a1 = fmaxf(fmaxf(sc0[4], sc0[5]), fmaxf(sc0[6], sc0[7]));
    float a2 = fmaxf(fmaxf(sc0[8], sc0[9]), fmaxf(sc0[10], sc0[11]));
    float a3 = fmaxf(fmaxf(sc0[12], sc0[13]), fmaxf(sc0[14], sc0[15]));
    float b0 = fmaxf(fmaxf(sc1[0], sc1[1]), fmaxf(sc1[2], sc1[3]));
    float b1 = fmaxf(fmaxf(sc1[4], sc1[5]), fmaxf(sc1[6], sc1[7]));
    float b2 = fmaxf(fmaxf(sc1[8], sc1[9]), fmaxf(sc1[10], sc1[11]));
    float b3 = fmaxf(fmaxf(sc1[12], sc1[13]), fmaxf(sc1[14], sc1[15]));
    float pm = fmaxf(fmaxf(fmaxf(a0, a1), fmaxf(a2, a3)),
                     fmaxf(fmaxf(b0, b1), fmaxf(b2, b3)));
    if (!__all(pm <= m_run + 11.5f)) {
      float mx = fmaxf(pm, __shfl_xor(pm, 32, 64));
      mx = fmaxf(mx, m_run);
      const float alpha = __builtin_amdgcn_exp2f(m_run - mx);
      m_run = mx;
      l_part *= alpha;
#pragma unroll
      for (int r = 0; r < 16; ++r) { oacc0[r] *= alpha; oacc1[r] *= alpha; }
    }

    // P = exp2(S - m) in-register
    float p0[16], p1[16];
#pragma unroll
    for (int r = 0; r < 16; ++r) p0[r] = __builtin_amdgcn_exp2f(sc0[r] - m_run);
#pragma unroll
    for (int r = 0; r < 16; ++r) p1[r] = __builtin_amdgcn_exp2f(sc1[r] - m_run);
    float s00 = ((p0[0] + p0[1]) + (p0[2] + p0[3])) +
                ((p0[4] + p0[5]) + (p0[6] + p0[7]));
    float s01 = ((p0[8] + p0[9]) + (p0[10] + p0[11])) +
                ((p0[12] + p0[13]) + (p0[14] + p0[15]));
    float s10 = ((p1[0] + p1[1]) + (p1[2] + p1[3])) +
                ((p1[4] + p1[5]) + (p1[6] + p1[7]));
    float s11 = ((p1[8] + p1[9]) + (p1[10] + p1[11])) +
                ((p1[12] + p1[13]) + (p1[14] + p1[15]));
    l_part += (s00 + s01) + (s10 + s11);

    // pack: u[j] = (p[2j], p[2j+1]); reg r -> kv = (r&3) + 8*(r>>2) + 4*hi
    unsigned u0 = cvt_pk_bf16(p0[0], p0[1]),   u1 = cvt_pk_bf16(p0[2], p0[3]);
    unsigned u2 = cvt_pk_bf16(p0[4], p0[5]),   u3 = cvt_pk_bf16(p0[6], p0[7]);
    unsigned u4 = cvt_pk_bf16(p0[8], p0[9]),   u5 = cvt_pk_bf16(p0[10], p0[11]);
    unsigned u6 = cvt_pk_bf16(p0[12], p0[13]), u7 = cvt_pk_bf16(p0[14], p0[15]);
    unsigned u8 = cvt_pk_bf16(p1[0], p1[1]),   u9 = cvt_pk_bf16(p1[2], p1[3]);
    unsigned uA = cvt_pk_bf16(p1[4], p1[5]),   uB = cvt_pk_bf16(p1[6], p1[7]);
    unsigned uC = cvt_pk_bf16(p1[8], p1[9]),   uD = cvt_pk_bf16(p1[10], p1[11]);
    unsigned uE = cvt_pk_bf16(p1[12], p1[13]), uF = cvt_pk_bf16(p1[14], p1[15]);

    // redistribute across lane^32 pair
    union { unsigned wd[4]; bf16x8 v; } pk0, pk1, pk2, pk3;
    {
      unsigned x0 = __shfl_xor(u0, 32, 64), x1 = __shfl_xor(u1, 32, 64);
      unsigned x2 = __shfl_xor(u2, 32, 64), x3 = __shfl_xor(u3, 32, 64);
      pk0.wd[0] = hi ? x2 : u0; pk0.wd[1] = hi ? x3 : u1;
      pk0.wd[2] = hi ? u2 : x0; pk0.wd[3] = hi ? u3 : x1;
      unsigned y0 = __shfl_xor(u4, 32, 64), y1 = __shfl_xor(u5, 32, 64);
      unsigned y2 = __shfl_xor(u6, 32, 64), y3 = __shfl_xor(u7, 32, 64);
      pk1.wd[0] = hi ? y2 : u4; pk1.wd[1] = hi ? y3 : u5;
      pk1.wd[2] = hi ? u6 : y0; pk1.wd[3] = hi ? u7 : y1;
      unsigned z0 = __shfl_xor(u8, 32, 64), z1 = __shfl_xor(u9, 32, 64);
      unsigned z2 = __shfl_xor(uA, 32, 64), z3 = __shfl_xor(uB, 32, 64);
      pk2.wd[0] = hi ? z2 : u8; pk2.wd[1] = hi ? z3 : u9;
      pk2.wd[2] = hi ? uA : z0; pk2.wd[3] = hi ? uB : z1;
      unsigned q0 = __shfl_xor(uC, 32, 64), q1 = __shfl_xor(uD, 32, 64);
      unsigned q2 = __shfl_xor(uE, 32, 64), q3 = __shfl_xor(uF, 32, 64);
      pk3.wd[0] = hi ? q2 : uC; pk3.wd[1] = hi ? q3 : uD;
      pk3.wd[2] = hi ? uE : q0; pk3.wd[3] = hi ? uF : q1;
    }

    // O^T += V^T @ P^T
    __builtin_amdgcn_s_setprio(1);
    {
      bf16x8 vf;
      vf = frag_ld(vTc, l31, gb + 0);  oacc0 = mfma32(vf, pk0.v, oacc0);
      vf = frag_ld(vTc, l31, gb + 32); oacc0 = mfma32(vf, pk1.v, oacc0);
      vf = frag_ld(vTc, l31, gb + 64); oacc0 = mfma32(vf, pk2.v, oacc0);
      vf = frag_ld(vTc, l31, gb + 96); oacc0 = mfma32(vf, pk3.v, oacc0);
      vf = frag_ld(vTc, 32 + l31, gb + 0);  oacc1 = mfma32(vf, pk0.v, oacc1);
      vf = frag_ld(vTc, 32 + l31, gb + 32); oacc1 = mfma32(vf, pk1.v, oacc1);
      vf = frag_ld(vTc, 32 + l31, gb + 64); oacc1 = mfma32(vf, pk2.v, oacc1);
      vf = frag_ld(vTc, 32 + l31, gb + 96); oacc1 = mfma32(vf, pk3.v, oacc1);
    }
    __builtin_amdgcn_s_setprio(0);
  };

  // prologue: tiles 0 and 1 staged; wait tile 0 only (tile 1 in flight)
  STAGE_KV(0, 0);
  STAGE_KV(1, 1);
  asm volatile("s_waitcnt vmcnt(8)" ::: "memory");
  __builtin_amdgcn_s_barrier();

  // main loop: stage kt+2, compute kt, wait vmcnt(8) (= tile kt+1 landed,
  // tile kt+2's 8 loads remain in flight across the raw barrier)
  for (int kt = 0; kt < 30; ++kt) {
    int cur = kt % 3;
    int nb = cur + 2; if (nb >= 3) nb -= 3;
    STAGE_KV(kt + 2, nb);
    COMPUTE(kT[cur], vT[cur]);
    asm volatile("s_waitcnt vmcnt(8) lgkmcnt(0)" ::: "memory");
    __builtin_amdgcn_s_barrier();
  }
  // kt = 30 (buf 0): wait remaining stage-31 loads fully
  COMPUTE(kT[0], vT[0]);
  asm volatile("s_waitcnt vmcnt(0) lgkmcnt(0)" ::: "memory");
  __builtin_amdgcn_s_barrier();
  // kt = 31 (buf 1)
  COMPUTE(kT[1], vT[1]);

  // final row sum (own half + partner half), then store O
  float rs = l_part + __shfl_xor(l_part, 32, 64);
  const float inv = 1.f / rs;
  const int b = bh >> 4, h = bh & 15;
  const long qrow = (long)qt * 64 + w * 32 + l31;
  unsigned short* orow = o + ((long)b * 2048 + qrow) * 1024 + h * 64;
#pragma unroll
  for (int rq = 0; rq < 4; ++rq) {
    uint2 pk;
    pk.x = cvt_pk_bf16(oacc0[rq * 4 + 0] * inv, oacc0[rq * 4 + 1] * inv);
    pk.y = cvt_pk_bf16(oacc0[rq * 4 + 2] * inv, oacc0[rq * 4 + 3] * inv);
    *(uint2*)(orow + rq * 8 + hi * 4) = pk;
  }
#pragma unroll
  for (int rq = 0; rq < 4; ++rq) {
    uint2 pk;
    pk.x = cvt_pk_bf16(oacc1[rq * 4 + 0] * inv, oacc1[rq * 4 + 1] * inv);
    pk.y = cvt_pk_bf16(oacc1[rq * 4 + 2] * inv, oacc1[rq * 4 + 3] * inv);
    *(uint2*)(orow + 32 + rq * 8 + hi * 4) = pk;
  }
#undef STAGE_KV
}

// ---------------- output projection ----------------
__global__ __launch_bounds__(256) void out_gemm(const unsigned short* __restrict__ ab,
                                                const unsigned short* __restrict__ wb,
                                                const float* __restrict__ bias,
                                                float* __restrict__ out) {
  __shared__ __align__(16) unsigned short aT[128 * 64];
  __shared__ __align__(16) unsigned short bT[128 * 64];
  const int tid = threadIdx.x, l = tid & 63, w = tid >> 6;
  const int swz = xcd_swz(blockIdx.y * 8 + blockIdx.x, 8 * 32);
  const int bx = swz % 8, by = swz / 8;
  const long m0 = (long)by * 128, n0 = (long)bx * 128;
  f32x4 acc[4][4] = {};
  gemm_loop(ab, wb, m0, n0, aT, bT, w, l, acc);

  const int wr = (w >> 1) * 64, wc = (w & 1) * 64;
  const int l15 = l & 15, lg = l >> 4;
#pragma unroll
  for (int nt = 0; nt < 4; ++nt) {
    const int n = (int)n0 + wc + nt * 16 + l15;
    const float bv = bias[n];
#pragma unroll
    for (int mt = 0; mt < 4; ++mt) {
#pragma unroll
      for (int j = 0; j < 4; ++j) {
        const long m = m0 + wr + mt * 16 + lg * 4 + j;
        out[m * 1024 + n] = acc[mt][nt][j] + bv;
      }
    }
  }
}

extern "C" void kernel_launch(void* const* d_in, const int* in_sizes, int n_in,
                              void* d_out, int out_size, void* d_ws, size_t ws_size,
                              hipStream_t stream) {
  const float* x = (const float*)d_in[0];
  const float* qkv_w = (const float*)d_in[1];
  const float* qkv_b = (const float*)d_in[2];
  const float* out_w = (const float*)d_in[3];
  const float* out_b = (const float*)d_in[4];
  const float* akmin = (const float*)d_in[5];
  const float* akmax = (const float*)d_in[6];
  const float* avmin = (const float*)d_in[7];
  const float* avmax = (const float*)d_in[8];

  char* ws = (char*)d_ws;
  const long MB = 1024 * 1024;
  unsigned short* xb  = (unsigned short*)(ws + 0 * MB);    // 8 MB  [4096][1024]
  unsigned short* wqb = (unsigned short*)(ws + 8 * MB);    // 6 MB  [3072][1024]
  unsigned short* wob = (unsigned short*)(ws + 14 * MB);   // 2 MB  [1024][1024]
  unsigned short* qb  = (unsigned short*)(ws + 16 * MB);   // 8 MB  [32][2048][64] (q*QSCALE)
  unsigned short* kb  = (unsigned short*)(ws + 24 * MB);   // 8 MB  [32][2048][64]
  unsigned short* vtb = (unsigned short*)(ws + 32 * MB);   // 8 MB  [32][64][2048]
  unsigned short* ob  = (unsigned short*)(ws + 40 * MB);   // 8 MB  [4096][1024]

  cvt_f32_bf16<<<4096, 256, 0, stream>>>(x, xb, 4096 * 1024 / 4);
  cvt_f32_bf16<<<3072, 256, 0, stream>>>(qkv_w, wqb, 3072 * 1024 / 4);
  cvt_f32_bf16<<<1024, 256, 0, stream>>>(out_w, wob, 1024 * 1024 / 4);
  qkv_gemm<<<dim3(24, 32), 256, 0, stream>>>(xb, wqb, qkv_b, akmin, akmax, avmin,
                                             avmax, qb, kb, vtb);
  attn_fwd<<<dim3(32, 32), 128, 0, stream>>>(qb, kb, vtb, ob);
  out_gemm<<<dim3(8, 32), 256, 0, stream>>>(ob, wob, out_b, (float*)d_out);
}

// Round 13
// 132.749 us; speedup vs baseline: 1.3878x; 1.3878x over previous
//
#include <hip/hip_runtime.h>

// Range-aware attention, bf16 MFMA pipeline.
// B=2, S=2048, D=1024, H=16, dk=64. EPS=0.1.

typedef __bf16 bf16x8 __attribute__((ext_vector_type(8)));
typedef float f32x4 __attribute__((ext_vector_type(4)));

#define EPSG 0.1f
// q pre-scale: 1/sqrt(dk) * log2(e)  -> scores come out in log2 domain
#define QSCALE 0.180336880f

__device__ __forceinline__ unsigned short f2bf(float f) {
  unsigned int u = __float_as_uint(f);
  u += 0x7FFFu + ((u >> 16) & 1u);   // RNE
  return (unsigned short)(u >> 16);
}

__device__ __forceinline__ unsigned cvt_pk_bf16(float a, float b) {
  unsigned r;
  asm("v_cvt_pk_bf16_f32 %0, %1, %2" : "=v"(r) : "v"(a), "v"(b));
  return r;  // lo16 = bf16(a), hi16 = bf16(b)
}

__device__ __forceinline__ void gload_lds16(const void* g, void* l) {
  __builtin_amdgcn_global_load_lds(
      (const __attribute__((address_space(1))) void*)g,
      (__attribute__((address_space(3))) void*)l, 16, 0, 0);
}

// ---------------- fp32 -> bf16 cast (all three inputs, one launch) ----------
__global__ __launch_bounds__(256) void cvt_all(const float* __restrict__ x,
                                               const float* __restrict__ wq,
                                               const float* __restrict__ wo,
                                               unsigned short* __restrict__ xb,
                                               unsigned short* __restrict__ wqb,
                                               unsigned short* __restrict__ wob) {
  const int i = blockIdx.x * 256 + threadIdx.x;  // float4 index, 2M total
  const float* in;
  unsigned short* out;
  int j;
  if (i < 1048576) {            // x: 4M floats
    in = x; out = xb; j = i;
  } else if (i < 1835008) {     // qkv_w: 3M floats
    in = wq; out = wqb; j = i - 1048576;
  } else {                      // out_w: 1M floats
    in = wo; out = wob; j = i - 1835008;
  }
  float4 v = ((const float4*)in)[j];
  ushort4 o;
  o.x = f2bf(v.x); o.y = f2bf(v.y); o.z = f2bf(v.z); o.w = f2bf(v.w);
  ((ushort4*)out)[j] = o;
}

// ---------------- shared GEMM pieces ----------------
__device__ __forceinline__ void stage128x64(const unsigned short* __restrict__ g,
                                            long ldb, long row0, long k0b,
                                            unsigned short* lds, int w, int l) {
  const char* gp = (const char*)g + (row0 + (long)(w * 8 + (l >> 3))) * ldb + k0b +
                   (long)(((l & 7) ^ (l >> 3)) << 4);
  char* lp = (char*)lds + w * 1024;
#pragma unroll
  for (int i = 0; i < 4; ++i) {
    gload_lds16(gp + (long)i * 32 * ldb, lp + i * 4096);
  }
}

__device__ __forceinline__ bf16x8 frag_ld(const unsigned short* lds, int row, int cb) {
  return *(const bf16x8*)((const char*)lds + row * 128 + (cb ^ ((row & 7) << 4)));
}

// XCD-chunked bijective block swizzle (T1): nwg must be divisible by 8.
__device__ __forceinline__ int xcd_swz(int lin, int nwg) {
  return (lin & 7) * (nwg >> 3) + (lin >> 3);
}

// 128x128 output tile, K=1024, A and B^T both row-major with 2048-byte rows.
__device__ __forceinline__ void gemm_loop(const unsigned short* __restrict__ A,
                                          const unsigned short* __restrict__ Bm,
                                          long m0, long n0,
                                          unsigned short* aT, unsigned short* bT,
                                          int w, int l, f32x4 acc[4][4]) {
  const int wr = (w >> 1) * 64, wc = (w & 1) * 64;
  const int l15 = l & 15;
  for (int ks = 0; ks < 1024; ks += 64) {
    __syncthreads();
    stage128x64(A, 2048, m0, (long)ks * 2, aT, w, l);
    stage128x64(Bm, 2048, n0, (long)ks * 2, bT, w, l);
    __syncthreads();
#pragma unroll
    for (int kk = 0; kk < 2; ++kk) {
      const int cb = kk * 64 + (l >> 4) * 16;
      bf16x8 af[4], bfr[4];
#pragma unroll
      for (int t = 0; t < 4; ++t) af[t] = frag_ld(aT, wr + t * 16 + l15, cb);
#pragma unroll
      for (int t = 0; t < 4; ++t) bfr[t] = frag_ld(bT, wc + t * 16 + l15, cb);
#pragma unroll
      for (int mt = 0; mt < 4; ++mt)
#pragma unroll
        for (int nt = 0; nt < 4; ++nt)
          acc[mt][nt] = __builtin_amdgcn_mfma_f32_16x16x32_bf16(af[mt], bfr[nt],
                                                                acc[mt][nt], 0, 0, 0);
    }
  }
}

// ---------------- QKV projection + clamp + layout scatter ----------------
// q stored PRE-SCALED by QSCALE (1/8 * log2e).  q,k -> [B*H][S][64]; v -> [B*H][64][S].
__global__ __launch_bounds__(256) void qkv_gemm(
    const unsigned short* __restrict__ xb, const unsigned short* __restrict__ wb,
    const float* __restrict__ bias,
    const float* __restrict__ akmin, const float* __restrict__ akmax,
    const float* __restrict__ avmin, const float* __restrict__ avmax,
    unsigned short* __restrict__ qo, unsigned short* __restrict__ ko,
    unsigned short* __restrict__ vto) {
  __shared__ __align__(16) unsigned short aT[128 * 64];
  __shared__ __align__(16) unsigned short bT[128 * 64];
  const int tid = threadIdx.x, l = tid & 63, w = tid >> 6;
  const int swz = xcd_swz(blockIdx.y * 24 + blockIdx.x, 24 * 32);
  const int bx = swz % 24, by = swz / 24;
  const long m0 = (long)by * 128, n0 = (long)bx * 128;
  f32x4 acc[4][4] = {};
  gemm_loop(xb, wb, m0, n0, aT, bT, w, l, acc);

  const int wr = (w >> 1) * 64, wc = (w & 1) * 64;
  const int l15 = l & 15, lg = l >> 4;
  const int t = (int)(n0 >> 10);  // uniform per block
#pragma unroll
  for (int nt = 0; nt < 4; ++nt) {
    const int n = (int)n0 + wc + nt * 16 + l15;
    const float bv = bias[n];
    const int h = (n >> 6) & 15, d = n & 63;
#pragma unroll
    for (int mt = 0; mt < 4; ++mt) {
      const long s0 = m0 + wr + mt * 16 + lg * 4;
      const int b = (int)(s0 >> 11), s_lo = (int)(s0 & 2047);
      const int bh = b * 16 + h;
      if (t == 0) {
#pragma unroll
        for (int j = 0; j < 4; ++j) {
          float v = (acc[mt][nt][j] + bv) * QSCALE;
          qo[((long)bh * 2048 + s_lo + j) * 64 + d] = f2bf(v);
        }
      } else if (t == 1) {
        const int ai = bh * 64 + d;
        const float amn = akmin[ai], amx = akmax[ai];
#pragma unroll
        for (int j = 0; j < 4; ++j) {
          float v = acc[mt][nt][j] + bv;
          float lo = fmaxf(v - EPSG, amn);
          float hi = fminf(v + EPSG, amx);
          lo = fminf(lo, hi);
          v = fmaxf(lo, fminf(v, hi));
          ko[((long)bh * 2048 + s_lo + j) * 64 + d] = f2bf(v);
        }
      } else {
        const int ai = bh * 64 + d;
        const float amn = avmin[ai], amx = avmax[ai];
        ushort4 pk;
        unsigned short* pp = (unsigned short*)&pk;
#pragma unroll
        for (int j = 0; j < 4; ++j) {
          float v = acc[mt][nt][j] + bv;
          float lo = fmaxf(v - EPSG, amn);
          float hi = fminf(v + EPSG, amx);
          lo = fminf(lo, hi);
          v = fmaxf(lo, fminf(v, hi));
          pp[j] = f2bf(v);
        }
        *(ushort4*)(vto + ((long)bh * 64 + d) * 2048 + s_lo) = pk;
      }
    }
  }
}

// ---------------- flash attention ----------------
// OCCUPANCY round: R9's verified per-wave compute VERBATIM; block = 8 waves
// sharing one K/V tile pair (48KB LDS), grid 512 -> 2 blocks/CU = 16 waves/CU
// guaranteed co-resident (vs R9's ~11). Each wave: 16 q-rows; staging = 2
// gloads/wave (was 4). Swapped operands; scores in log2 domain; defer-max.
__global__ __launch_bounds__(512) void attn_fwd(
    const unsigned short* __restrict__ q, const unsigned short* __restrict__ k,
    const unsigned short* __restrict__ vt, unsigned short* __restrict__ o) {
  __shared__ __align__(16) unsigned short kT[2][64 * 64];
  __shared__ __align__(16) unsigned short vT[2][64 * 64];
  __shared__ __align__(16) unsigned short p_lds[8 * 16 * 64];
  const int tid = threadIdx.x, l = tid & 63, w = tid >> 6;  // w in 0..7
  const int l15 = l & 15, lg = l >> 4;

  // XCD swizzle: 512 blocks; linear%8 = dispatch XCD; 4-bh chunk per XCD.
  const int linear = blockIdx.y * 16 + blockIdx.x;
  const int idx = linear >> 3;
  const int bh = (linear & 7) * 4 + (idx >> 4);
  const int qt = idx & 15;  // 128-row q tile

  const char* kbC = (const char*)(k + (long)bh * 2048 * 64);
  const char* vbC = (const char*)(vt + (long)bh * 64 * 2048);

  // Q fragments (pre-scaled); used as the B-operand of the swapped QK^T.
  const unsigned short* qbase = q + ((long)bh * 2048 + qt * 128 + w * 16) * 64;
  bf16x8 qf[2];
#pragma unroll
  for (int kk = 0; kk < 2; ++kk)
    qf[kk] = *(const bf16x8*)(qbase + (long)l15 * 64 + kk * 32 + lg * 8);

  float m_run = -1e30f, l_part = 0.f;
  f32x4 oacc[4] = {};  // oacc[dt][j] = O[q=l15][d = dt*16 + lg*4 + j]

  unsigned short* pw = p_lds + w * 1024;  // per-wave [16 q-rows][64 kv] bf16
  const int pswz = (l15 & 7) << 4;
  char* pwrow = (char*)pw + l15 * 128;
  const int srow = l >> 3;                    // 0..7
  const int schk = ((l & 7) ^ srow) << 4;     // pre-swizzled source chunk

// 8 waves each stage 8 rows of K and 8 rows of V (1 gload each).
#define STAGE_KV(kt_, buf_)                                                      \
  do {                                                                           \
    const char* sK = kbC + (long)((kt_)*64 + w * 8 + srow) * 128 + schk;         \
    gload_lds16(sK, (char*)kT[buf_] + w * 1024);                                 \
    const char* sV = vbC + (long)(w * 8 + srow) * 4096 + (long)(kt_)*128 + schk; \
    gload_lds16(sV, (char*)vT[buf_] + w * 1024);                                 \
  } while (0)

  STAGE_KV(0, 0);
  asm volatile("s_waitcnt vmcnt(0)" ::: "memory");
  __syncthreads();

  for (int kt = 0; kt < 32; ++kt) {
    const int cur = kt & 1;
    if (kt < 31) STAGE_KV(kt + 1, cur ^ 1);
    const unsigned short* kTc = kT[cur];
    const unsigned short* vTc = vT[cur];

    // S^T = K @ Q^T : sc[ct][j] = S[q=l15][kv = ct*16 + lg*4 + j]  (log2 domain)
    f32x4 sc[4] = {};
    __builtin_amdgcn_s_setprio(1);
#pragma unroll
    for (int kk = 0; kk < 2; ++kk) {
      const int cb = kk * 64 + lg * 16;
#pragma unroll
      for (int ct = 0; ct < 4; ++ct) {
        const int row = ct * 16 + l15;
        bf16x8 kf = *(const bf16x8*)((const char*)kTc + row * 128 +
                                     (cb ^ ((row & 7) << 4)));
        sc[ct] = __builtin_amdgcn_mfma_f32_16x16x32_bf16(kf, qf[kk], sc[ct], 0, 0, 0);
      }
    }
    __builtin_amdgcn_s_setprio(0);

    // per-lane tile max over the lane's 16 scores
    float pm = fmaxf(fmaxf(fmaxf(sc[0][0], sc[0][1]), fmaxf(sc[0][2], sc[0][3])),
                     fmaxf(fmaxf(sc[1][0], sc[1][1]), fmaxf(sc[1][2], sc[1][3])));
    pm = fmaxf(pm,
               fmaxf(fmaxf(fmaxf(sc[2][0], sc[2][1]), fmaxf(sc[2][2], sc[2][3])),
                     fmaxf(fmaxf(sc[3][0], sc[3][1]), fmaxf(sc[3][2], sc[3][3]))));
    if (!__all(pm <= m_run + 11.5f)) {
      // slow path: row max = reduce across the 4 lanes sharing l15
      float mx = pm;
      mx = fmaxf(mx, __shfl_xor(mx, 16, 64));
      mx = fmaxf(mx, __shfl_xor(mx, 32, 64));
      mx = fmaxf(mx, m_run);
      const float alpha = __builtin_amdgcn_exp2f(m_run - mx);
      m_run = mx;
      l_part *= alpha;
#pragma unroll
      for (int dt = 0; dt < 4; ++dt) oacc[dt] *= alpha;
    }
    // P = exp2(S - m); pack pairs; 4x ds_write_b64 into per-wave P slab
    float rs = 0.f;
#pragma unroll
    for (int ct = 0; ct < 4; ++ct) {
      const float p0 = __builtin_amdgcn_exp2f(sc[ct][0] - m_run);
      const float p1 = __builtin_amdgcn_exp2f(sc[ct][1] - m_run);
      const float p2 = __builtin_amdgcn_exp2f(sc[ct][2] - m_run);
      const float p3 = __builtin_amdgcn_exp2f(sc[ct][3] - m_run);
      rs += (p0 + p1) + (p2 + p3);
      uint2 pk;
      pk.x = cvt_pk_bf16(p0, p1);
      pk.y = cvt_pk_bf16(p2, p3);
      *(uint2*)(pwrow + ((ct * 32 + lg * 8) ^ pswz)) = pk;
    }
    l_part += rs;

    // O^T += V^T @ P^T : oacc[dt] = mfma(vf[dt], pf[kk])
    __builtin_amdgcn_s_setprio(1);
#pragma unroll
    for (int kk = 0; kk < 2; ++kk) {
      const int cb = kk * 64 + lg * 16;
      bf16x8 pf = *(const bf16x8*)(pwrow + (cb ^ pswz));
#pragma unroll
      for (int dt = 0; dt < 4; ++dt) {
        const int row = dt * 16 + l15;
        bf16x8 vf = *(const bf16x8*)((const char*)vTc + row * 128 +
                                     (cb ^ ((row & 7) << 4)));
        oacc[dt] = __builtin_amdgcn_mfma_f32_16x16x32_bf16(vf, pf, oacc[dt], 0, 0, 0);
      }
    }
    __builtin_amdgcn_s_setprio(0);
    asm volatile("s_waitcnt vmcnt(0)" ::: "memory");
    __syncthreads();
  }

  // final row-sum across the 4 lanes sharing l15
  float rs = l_part;
  rs += __shfl_xor(rs, 16, 64);
  rs += __shfl_xor(rs, 32, 64);
  const float inv = 1.f / rs;

  const int b = bh >> 4, h = bh & 15;
  const long s = (long)qt * 128 + w * 16 + l15;
  unsigned short* orow = o + ((long)b * 2048 + s) * 1024 + h * 64;
#pragma unroll
  for (int dt = 0; dt < 4; ++dt) {
    uint2 pk;
    pk.x = cvt_pk_bf16(oacc[dt][0] * inv, oacc[dt][1] * inv);
    pk.y = cvt_pk_bf16(oacc[dt][2] * inv, oacc[dt][3] * inv);
    *(uint2*)(orow + dt * 16 + lg * 4) = pk;
  }
#undef STAGE_KV
}

// ---------------- output projection ----------------
__global__ __launch_bounds__(256) void out_gemm(const unsigned short* __restrict__ ab,
                                                const unsigned short* __restrict__ wb,
                                                const float* __restrict__ bias,
                                                float* __restrict__ out) {
  __shared__ __align__(16) unsigned short aT[128 * 64];
  __shared__ __align__(16) unsigned short bT[128 * 64];
  const int tid = threadIdx.x, l = tid & 63, w = tid >> 6;
  const int swz = xcd_swz(blockIdx.y * 8 + blockIdx.x, 8 * 32);
  const int bx = swz % 8, by = swz / 8;
  const long m0 = (long)by * 128, n0 = (long)bx * 128;
  f32x4 acc[4][4] = {};
  gemm_loop(ab, wb, m0, n0, aT, bT, w, l, acc);

  const int wr = (w >> 1) * 64, wc = (w & 1) * 64;
  const int l15 = l & 15, lg = l >> 4;
#pragma unroll
  for (int nt = 0; nt < 4; ++nt) {
    const int n = (int)n0 + wc + nt * 16 + l15;
    const float bv = bias[n];
#pragma unroll
    for (int mt = 0; mt < 4; ++mt) {
#pragma unroll
      for (int j = 0; j < 4; ++j) {
        const long m = m0 + wr + mt * 16 + lg * 4 + j;
        out[m * 1024 + n] = acc[mt][nt][j] + bv;
      }
    }
  }
}

extern "C" void kernel_launch(void* const* d_in, const int* in_sizes, int n_in,
                              void* d_out, int out_size, void* d_ws, size_t ws_size,
                              hipStream_t stream) {
  const float* x = (const float*)d_in[0];
  const float* qkv_w = (const float*)d_in[1];
  const float* qkv_b = (const float*)d_in[2];
  const float* out_w = (const float*)d_in[3];
  const float* out_b = (const float*)d_in[4];
  const float* akmin = (const float*)d_in[5];
  const float* akmax = (const float*)d_in[6];
  const float* avmin = (const float*)d_in[7];
  const float* avmax = (const float*)d_in[8];

  char* ws = (char*)d_ws;
  const long MB = 1024 * 1024;
  unsigned short* xb  = (unsigned short*)(ws + 0 * MB);    // 8 MB  [4096][1024]
  unsigned short* wqb = (unsigned short*)(ws + 8 * MB);    // 6 MB  [3072][1024]
  unsigned short* wob = (unsigned short*)(ws + 14 * MB);   // 2 MB  [1024][1024]
  unsigned short* qb  = (unsigned short*)(ws + 16 * MB);   // 8 MB  [32][2048][64] (q*QSCALE)
  unsigned short* kb  = (unsigned short*)(ws + 24 * MB);   // 8 MB  [32][2048][64]
  unsigned short* vtb = (unsigned short*)(ws + 32 * MB);   // 8 MB  [32][64][2048]
  unsigned short* ob  = (unsigned short*)(ws + 40 * MB);   // 8 MB  [4096][1024]

  cvt_all<<<8192, 256, 0, stream>>>(x, qkv_w, out_w, xb, wqb, wob);
  qkv_gemm<<<dim3(24, 32), 256, 0, stream>>>(xb, wqb, qkv_b, akmin, akmax, avmin,
                                             avmax, qb, kb, vtb);
  attn_fwd<<<dim3(16, 32), 512, 0, stream>>>(qb, kb, vtb, ob);
  out_gemm<<<dim3(8, 32), 256, 0, stream>>>(ob, wob, out_b, (float*)d_out);
}